// Round 1
// baseline (631.012 us; speedup 1.0000x reference)
//
#include <hip/hip_runtime.h>
#include <math.h>

#define NN 50000
#define NE 800000
#define HC 128
#define NHEAD 4
#define EMB 64

__device__ __forceinline__ float lrelu(float x) { return x > 0.0f ? x : 0.2f * x; }
__device__ __forceinline__ float gelu_f(float x) {
    return 0.5f * x * (1.0f + erff(x * 0.70710678118654752440f));
}
__device__ __forceinline__ float sel4(float4 v, int h) {
    float r = v.x;
    r = (h == 1) ? v.y : r;
    r = (h == 2) ? v.z : r;
    r = (h == 3) ? v.w : r;
    return r;
}

// ---------------- frontend ----------------
__global__ void stats_kernel(const float* __restrict__ rq, float* __restrict__ stats) {
    int i = blockIdx.x * blockDim.x + threadIdx.x;
    float s = 0.f, s2 = 0.f;
    for (; i < NN; i += gridDim.x * blockDim.x) {
        float v = rq[i];
        s += v; s2 += v * v;
    }
    #pragma unroll
    for (int off = 32; off > 0; off >>= 1) {
        s  += __shfl_down(s, off);
        s2 += __shfl_down(s2, off);
    }
    __shared__ float ls[8], ls2[8];
    int lane = threadIdx.x & 63, wid = threadIdx.x >> 6;
    if (lane == 0) { ls[wid] = s; ls2[wid] = s2; }
    __syncthreads();
    if (threadIdx.x == 0) {
        float a = 0.f, b = 0.f;
        int nw = blockDim.x >> 6;
        for (int w = 0; w < nw; w++) { a += ls[w]; b += ls2[w]; }
        atomicAdd(&stats[0], a);
        atomicAdd(&stats[1], b);
    }
}

__global__ void build_x_kernel(const int* __restrict__ label, const float* __restrict__ rq,
                               const float* __restrict__ emb, const float* __restrict__ reqW,
                               const float* __restrict__ reqb, const float* __restrict__ stats,
                               float* __restrict__ x) {
    float sum = stats[0], sumsq = stats[1];
    float mean = sum / (float)NN;
    float var = (sumsq - sum * sum / (float)NN) / (float)(NN - 1);
    float inv = 1.0f / (sqrtf(var) + 1e-6f);
    int idx = blockIdx.x * blockDim.x + threadIdx.x;
    const int total = NN * HC;
    for (; idx < total; idx += gridDim.x * blockDim.x) {
        int n = idx >> 7, c = idx & 127;
        float v;
        if (c < EMB) {
            v = emb[label[n] * EMB + c];
        } else {
            float r = (rq[n] - mean) * inv;
            v = r * reqW[c - EMB] + reqb[c - EMB];
        }
        x[idx] = v;
    }
}

// ---------------- CSR build ----------------
__global__ void hist_kernel(const int* __restrict__ dst, int* __restrict__ deg) {
    int i = blockIdx.x * blockDim.x + threadIdx.x;
    if (i < NE) atomicAdd(&deg[dst[i]], 1);
}

__global__ void scan1_kernel(const int* __restrict__ deg, int* __restrict__ row_excl,
                             int* __restrict__ bsum) {
    __shared__ int tmp[256];
    int t = threadIdx.x;
    int i = blockIdx.x * 256 + t;
    int v = (i < NN) ? deg[i] : 0;
    tmp[t] = v;
    __syncthreads();
    #pragma unroll
    for (int off = 1; off < 256; off <<= 1) {
        int add = (t >= off) ? tmp[t - off] : 0;
        __syncthreads();
        tmp[t] += add;
        __syncthreads();
    }
    if (i < NN) row_excl[i] = tmp[t] - v;
    if (t == 255) bsum[blockIdx.x] = tmp[255];
}

__global__ void scan2_kernel(int* __restrict__ bsum, int nb) {
    __shared__ int tmp[256];
    int t = threadIdx.x;
    int v = (t < nb) ? bsum[t] : 0;
    tmp[t] = v;
    __syncthreads();
    #pragma unroll
    for (int off = 1; off < 256; off <<= 1) {
        int add = (t >= off) ? tmp[t - off] : 0;
        __syncthreads();
        tmp[t] += add;
        __syncthreads();
    }
    if (t < nb) bsum[t] = tmp[t] - v;  // exclusive block offsets
}

__global__ void scan3_kernel(int* __restrict__ row_excl, const int* __restrict__ bsum) {
    int i = blockIdx.x * blockDim.x + threadIdx.x;
    if (i < NN) row_excl[i] += bsum[i >> 8];
    if (i == 0) row_excl[NN] = NE;
}

__global__ void scatter_kernel(const int* __restrict__ src, const int* __restrict__ dst,
                               const int* __restrict__ row_start, int* __restrict__ cursor,
                               int* __restrict__ src_sorted) {
    int i = blockIdx.x * blockDim.x + threadIdx.x;
    if (i < NE) {
        int d = dst[i];
        int pos = row_start[d] + atomicAdd(&cursor[d], 1);
        src_sorted[pos] = src[i];
    }
}

// ---------------- per-layer GEMM: h = x @ W  (x:[NN,128], W:[128,128]) ----------------
__launch_bounds__(256)
__global__ void gemm_kernel(const float* __restrict__ x, const float* __restrict__ W,
                            float* __restrict__ h) {
    __shared__ float sW[128 * 128];   // 64 KB
    __shared__ float sX[128][68];     // x^T tile [k][row], pad 68 keeps 16B align
    int t = threadIdx.x;
    int row0 = blockIdx.x * 64;

    const float4* W4 = (const float4*)W;
    float4* sW4 = (float4*)sW;
    for (int i = t; i < 4096; i += 256) sW4[i] = W4[i];

    for (int i = t; i < 2048; i += 256) {
        int r = i >> 5;      // 0..63
        int k4 = i & 31;     // 0..31
        int rr = row0 + r;
        float4 v = make_float4(0.f, 0.f, 0.f, 0.f);
        if (rr < NN) v = ((const float4*)(x + (size_t)rr * 128))[k4];
        sX[4 * k4 + 0][r] = v.x;
        sX[4 * k4 + 1][r] = v.y;
        sX[4 * k4 + 2][r] = v.z;
        sX[4 * k4 + 3][r] = v.w;
    }
    __syncthreads();

    int tr = t >> 5;   // 0..7 -> rows tr*8 .. tr*8+7
    int tc = t & 31;   // cols tc*4 .. tc*4+3
    float acc[8][4] = {};
    for (int k = 0; k < 128; k++) {
        float4 wv = *(const float4*)(&sW[k * 128 + tc * 4]);
        float xr[8];
        #pragma unroll
        for (int j = 0; j < 8; j++) xr[j] = sX[k][tr * 8 + j];
        #pragma unroll
        for (int j = 0; j < 8; j++) {
            acc[j][0] += xr[j] * wv.x;
            acc[j][1] += xr[j] * wv.y;
            acc[j][2] += xr[j] * wv.z;
            acc[j][3] += xr[j] * wv.w;
        }
    }
    #pragma unroll
    for (int j = 0; j < 8; j++) {
        int rr = row0 + tr * 8 + j;
        if (rr < NN)
            *(float4*)(&h[(size_t)rr * 128 + tc * 4]) =
                make_float4(acc[j][0], acc[j][1], acc[j][2], acc[j][3]);
    }
}

// ---------------- per-node head projections ----------------
__global__ void al_kernel(const float* __restrict__ h, const float* __restrict__ a_src,
                          const float* __restrict__ a_dst, float* __restrict__ als,
                          float* __restrict__ ald) {
    int node = (blockIdx.x * blockDim.x + threadIdx.x) >> 6;
    int lane = threadIdx.x & 63;
    if (node >= NN) return;
    int c = lane * 2;
    float2 hv = *(const float2*)(h + (size_t)node * 128 + c);
    float2 as = *(const float2*)(a_src + c);   // [4,32] flat == channel index
    float2 ad = *(const float2*)(a_dst + c);
    float ps = hv.x * as.x + hv.y * as.y;
    float pd = hv.x * ad.x + hv.y * ad.y;
    #pragma unroll
    for (int off = 1; off < 16; off <<= 1) {
        ps += __shfl_xor(ps, off);
        pd += __shfl_xor(pd, off);
    }
    if ((lane & 15) == 0) {
        int hh = lane >> 4;
        als[node * 4 + hh] = ps;
        ald[node * 4 + hh] = pd;
    }
}

// ---------------- per-node softmax aggregation (one wave per node) ----------------
__launch_bounds__(256)
__global__ void agg_kernel(const float* __restrict__ h, const float* __restrict__ als_,
                           const float* __restrict__ ald_, const int* __restrict__ row_start,
                           const int* __restrict__ src_sorted, const float* __restrict__ bias,
                           float* __restrict__ out) {
    int node = (blockIdx.x * blockDim.x + threadIdx.x) >> 6;
    int lane = threadIdx.x & 63;
    if (node >= NN) return;
    int hh = lane >> 4;     // head for this lane's 2 channels
    int c = lane * 2;

    float4 adv = *(const float4*)(ald_ + (size_t)node * 4);
    float4 avs = *(const float4*)(als_ + (size_t)node * 4);
    float4 esf = make_float4(lrelu(avs.x + adv.x), lrelu(avs.y + adv.y),
                             lrelu(avs.z + adv.z), lrelu(avs.w + adv.w));
    int start = row_start[node], end = row_start[node + 1];

    // pass 1: per-head max (edge-parallel), self-loop as init
    float4 m = esf;
    for (int j = start + lane; j < end; j += 64) {
        int s = src_sorted[j];
        float4 av = *(const float4*)(als_ + (size_t)s * 4);
        m.x = fmaxf(m.x, lrelu(av.x + adv.x));
        m.y = fmaxf(m.y, lrelu(av.y + adv.y));
        m.z = fmaxf(m.z, lrelu(av.z + adv.z));
        m.w = fmaxf(m.w, lrelu(av.w + adv.w));
    }
    #pragma unroll
    for (int off = 1; off < 64; off <<= 1) {
        m.x = fmaxf(m.x, __shfl_xor(m.x, off));
        m.y = fmaxf(m.y, __shfl_xor(m.y, off));
        m.z = fmaxf(m.z, __shfl_xor(m.z, off));
        m.w = fmaxf(m.w, __shfl_xor(m.w, off));
    }
    float m_h  = sel4(m, hh);
    float ad_h = sel4(adv, hh);
    float es_h = sel4(esf, hh);

    // pass 2: channel-parallel accumulate (2 ch/lane)
    float s_sum, acc0, acc1;
    {
        float p = __expf(es_h - m_h);   // self loop
        s_sum = p;
        float2 hv = *(const float2*)(h + (size_t)node * 128 + c);
        acc0 = hv.x * p;
        acc1 = hv.y * p;
    }
    for (int base = start; base < end; base += 64) {
        int cnt = end - base;
        if (cnt > 64) cnt = 64;
        int my = 0;
        if (base + lane < end) my = src_sorted[base + lane];
        for (int jj = 0; jj < cnt; jj++) {
            int s = __shfl(my, jj);
            float a = als_[(size_t)s * 4 + hh] + ad_h;
            a = lrelu(a);
            float p = __expf(a - m_h);
            s_sum += p;
            float2 hv = *(const float2*)(h + (size_t)s * 128 + c);
            acc0 += hv.x * p;
            acc1 += hv.y * p;
        }
    }
    float inv = 1.0f / (s_sum + 1e-16f);
    float o0 = gelu_f(acc0 * inv + bias[c]);
    float o1 = gelu_f(acc1 * inv + bias[c + 1]);
    *(float2*)(out + (size_t)node * 128 + c) = make_float2(o0, o1);
}

extern "C" void kernel_launch(void* const* d_in, const int* in_sizes, int n_in,
                              void* d_out, int out_size, void* d_ws, size_t ws_size,
                              hipStream_t stream) {
    const int*   label = (const int*)d_in[0];
    const int*   eidx  = (const int*)d_in[1];          // [2, NE]
    const float* rq    = (const float*)d_in[3];
    const float* emb   = (const float*)d_in[4];
    const float* reqW  = (const float*)d_in[5];
    const float* reqb  = (const float*)d_in[6];
    const float* W[3]    = {(const float*)d_in[7],  (const float*)d_in[11], (const float*)d_in[15]};
    const float* asrc[3] = {(const float*)d_in[8],  (const float*)d_in[12], (const float*)d_in[16]};
    const float* adst[3] = {(const float*)d_in[9],  (const float*)d_in[13], (const float*)d_in[17]};
    const float* bias[3] = {(const float*)d_in[10], (const float*)d_in[14], (const float*)d_in[18]};

    const int* e_src = eidx;
    const int* e_dst = eidx + NE;

    char* ws = (char*)d_ws;
    size_t off = 0;
    auto A = [&](size_t n) { size_t o = off; off += (n + 255) & ~(size_t)255; return o; };
    size_t o_deg   = A((size_t)NN * 4);        // zeroed
    size_t o_cur   = A((size_t)NN * 4);        // zeroed
    size_t o_stats = A(8);                     // zeroed
    size_t zero_bytes = off;
    size_t o_row   = A((size_t)(NN + 1) * 4);
    size_t o_bsum  = A(256 * 4);
    size_t o_srcS  = A((size_t)NE * 4);
    size_t o_x     = A((size_t)NN * 128 * 4);
    size_t o_h     = A((size_t)NN * 128 * 4);
    size_t o_als   = A((size_t)NN * 4 * 4);
    size_t o_ald   = A((size_t)NN * 4 * 4);
    (void)ws_size; (void)n_in; (void)in_sizes; (void)out_size;

    int*   deg    = (int*)(ws + o_deg);
    int*   cursor = (int*)(ws + o_cur);
    float* stats  = (float*)(ws + o_stats);
    int*   rowst  = (int*)(ws + o_row);
    int*   bsum   = (int*)(ws + o_bsum);
    int*   srcS   = (int*)(ws + o_srcS);
    float* x      = (float*)(ws + o_x);
    float* h      = (float*)(ws + o_h);
    float* als    = (float*)(ws + o_als);
    float* ald    = (float*)(ws + o_ald);

    hipMemsetAsync(ws, 0, zero_bytes, stream);

    // frontend
    stats_kernel<<<256, 256, 0, stream>>>(rq, stats);
    build_x_kernel<<<8192, 256, 0, stream>>>(label, rq, emb, reqW, reqb, stats, x);

    // CSR build (self-loops handled analytically in agg)
    const int nb_scan = (NN + 255) / 256;  // 196
    hist_kernel<<<(NE + 255) / 256, 256, 0, stream>>>(e_dst, deg);
    scan1_kernel<<<nb_scan, 256, 0, stream>>>(deg, rowst, bsum);
    scan2_kernel<<<1, 256, 0, stream>>>(bsum, nb_scan);
    scan3_kernel<<<nb_scan, 256, 0, stream>>>(rowst, bsum);
    scatter_kernel<<<(NE + 255) / 256, 256, 0, stream>>>(e_src, e_dst, rowst, cursor, srcS);

    // 3 GAT layers
    const int gemm_blocks = (NN + 63) / 64;        // 782
    const int wave_blocks = (NN * 64 + 255) / 256; // 12500
    float* xin = x;
    for (int l = 0; l < 3; l++) {
        gemm_kernel<<<gemm_blocks, 256, 0, stream>>>(xin, W[l], h);
        al_kernel<<<wave_blocks, 256, 0, stream>>>(h, asrc[l], adst[l], als, ald);
        float* dst_buf = (l == 2) ? (float*)d_out : x;
        agg_kernel<<<wave_blocks, 256, 0, stream>>>(h, als, ald, rowst, srcS, bias[l], dst_buf);
        xin = x;
    }
}

// Round 2
// 500.552 us; speedup vs baseline: 1.2606x; 1.2606x over previous
//
#include <hip/hip_runtime.h>
#include <math.h>

#define NN 50000
#define NE 800000
#define HC 128
#define NHEAD 4
#define EMB 64
#define BK 32

__device__ __forceinline__ float lrelu(float x) { return x > 0.0f ? x : 0.2f * x; }
__device__ __forceinline__ float gelu_f(float x) {
    return 0.5f * x * (1.0f + erff(x * 0.70710678118654752440f));
}
__device__ __forceinline__ float sel4(float4 v, int h) {
    float r = v.x;
    r = (h == 1) ? v.y : r;
    r = (h == 2) ? v.z : r;
    r = (h == 3) ? v.w : r;
    return r;
}

// ---------------- frontend ----------------
__global__ void stats_kernel(const float* __restrict__ rq, float* __restrict__ stats) {
    int i = blockIdx.x * blockDim.x + threadIdx.x;
    float s = 0.f, s2 = 0.f;
    for (; i < NN; i += gridDim.x * blockDim.x) {
        float v = rq[i];
        s += v; s2 += v * v;
    }
    #pragma unroll
    for (int off = 32; off > 0; off >>= 1) {
        s  += __shfl_down(s, off);
        s2 += __shfl_down(s2, off);
    }
    __shared__ float ls[8], ls2[8];
    int lane = threadIdx.x & 63, wid = threadIdx.x >> 6;
    if (lane == 0) { ls[wid] = s; ls2[wid] = s2; }
    __syncthreads();
    if (threadIdx.x == 0) {
        float a = 0.f, b = 0.f;
        int nw = blockDim.x >> 6;
        for (int w = 0; w < nw; w++) { a += ls[w]; b += ls2[w]; }
        atomicAdd(&stats[0], a);
        atomicAdd(&stats[1], b);
    }
}

__global__ void build_x_kernel(const int* __restrict__ label, const float* __restrict__ rq,
                               const float* __restrict__ emb, const float* __restrict__ reqW,
                               const float* __restrict__ reqb, const float* __restrict__ stats,
                               float* __restrict__ x) {
    float sum = stats[0], sumsq = stats[1];
    float mean = sum / (float)NN;
    float var = (sumsq - sum * sum / (float)NN) / (float)(NN - 1);
    float inv = 1.0f / (sqrtf(var) + 1e-6f);
    int idx = blockIdx.x * blockDim.x + threadIdx.x;
    const int total = NN * HC;
    for (; idx < total; idx += gridDim.x * blockDim.x) {
        int n = idx >> 7, c = idx & 127;
        float v;
        if (c < EMB) {
            v = emb[label[n] * EMB + c];
        } else {
            float r = (rq[n] - mean) * inv;
            v = r * reqW[c - EMB] + reqb[c - EMB];
        }
        x[idx] = v;
    }
}

// ---------------- CSR build ----------------
__global__ void hist_kernel(const int* __restrict__ dst, int* __restrict__ deg) {
    int i = blockIdx.x * blockDim.x + threadIdx.x;
    if (i < NE) atomicAdd(&deg[dst[i]], 1);
}

__global__ void scan1_kernel(const int* __restrict__ deg, int* __restrict__ row_excl,
                             int* __restrict__ bsum) {
    __shared__ int tmp[256];
    int t = threadIdx.x;
    int i = blockIdx.x * 256 + t;
    int v = (i < NN) ? deg[i] : 0;
    tmp[t] = v;
    __syncthreads();
    #pragma unroll
    for (int off = 1; off < 256; off <<= 1) {
        int add = (t >= off) ? tmp[t - off] : 0;
        __syncthreads();
        tmp[t] += add;
        __syncthreads();
    }
    if (i < NN) row_excl[i] = tmp[t] - v;
    if (t == 255) bsum[blockIdx.x] = tmp[255];
}

__global__ void scan2_kernel(int* __restrict__ bsum, int nb) {
    __shared__ int tmp[256];
    int t = threadIdx.x;
    int v = (t < nb) ? bsum[t] : 0;
    tmp[t] = v;
    __syncthreads();
    #pragma unroll
    for (int off = 1; off < 256; off <<= 1) {
        int add = (t >= off) ? tmp[t - off] : 0;
        __syncthreads();
        tmp[t] += add;
        __syncthreads();
    }
    if (t < nb) bsum[t] = tmp[t] - v;  // exclusive block offsets
}

__global__ void scan3_kernel(int* __restrict__ row_excl, const int* __restrict__ bsum) {
    int i = blockIdx.x * blockDim.x + threadIdx.x;
    if (i < NN) row_excl[i] += bsum[i >> 8];
    if (i == 0) row_excl[NN] = NE;
}

__global__ void scatter_kernel(const int* __restrict__ src, const int* __restrict__ dst,
                               const int* __restrict__ row_start, int* __restrict__ cursor,
                               int* __restrict__ src_sorted) {
    int i = blockIdx.x * blockDim.x + threadIdx.x;
    if (i < NE) {
        int d = dst[i];
        int pos = row_start[d] + atomicAdd(&cursor[d], 1);
        src_sorted[pos] = src[i];
    }
}

// ---- fused GEMM + attention projections: h = x@W ; als/ald = per-head dot ----
// block: 256 thr; 64 rows x 128 cols out. K-chunked LDS: sW 16KB + sX 8.3KB
__launch_bounds__(256)
__global__ void gemm_al_kernel(const float* __restrict__ x, const float* __restrict__ W,
                               const float* __restrict__ a_src, const float* __restrict__ a_dst,
                               float* __restrict__ h, float* __restrict__ als,
                               float* __restrict__ ald) {
    __shared__ float sW[BK][128];    // 16 KB
    __shared__ float sX[BK][65];     // [k][row], pad 65 -> conflict-free writes
    int t = threadIdx.x;
    int row0 = blockIdx.x * 64;
    int tr = t >> 5;   // 0..7 -> rows tr*8..tr*8+7
    int tc = t & 31;   // cols tc*4..tc*4+3

    float acc[8][4] = {};
    for (int kk = 0; kk < 128; kk += BK) {
        if (kk) __syncthreads();
        // stage W chunk [kk..kk+BK) x 128
        #pragma unroll
        for (int i = 0; i < 4; i++)
            ((float4*)&sW[0][0])[t + 256 * i] = ((const float4*)(W + kk * 128))[t + 256 * i];
        // stage x chunk transposed: 64 rows x BK k
        #pragma unroll
        for (int i = 0; i < 2; i++) {
            int ii = t + 256 * i;        // 0..511
            int r = ii >> 3;             // 0..63
            int k4 = ii & 7;             // float4 index within BK
            int rr = row0 + r;
            float4 v = make_float4(0.f, 0.f, 0.f, 0.f);
            if (rr < NN) v = *(const float4*)(x + (size_t)rr * 128 + kk + k4 * 4);
            sX[k4 * 4 + 0][r] = v.x;
            sX[k4 * 4 + 1][r] = v.y;
            sX[k4 * 4 + 2][r] = v.z;
            sX[k4 * 4 + 3][r] = v.w;
        }
        __syncthreads();
        #pragma unroll
        for (int k = 0; k < BK; k++) {
            float4 wv = *(const float4*)(&sW[k][tc * 4]);
            float xr[8];
            #pragma unroll
            for (int j = 0; j < 8; j++) xr[j] = sX[k][tr * 8 + j];
            #pragma unroll
            for (int j = 0; j < 8; j++) {
                acc[j][0] += xr[j] * wv.x;
                acc[j][1] += xr[j] * wv.y;
                acc[j][2] += xr[j] * wv.z;
                acc[j][3] += xr[j] * wv.w;
            }
        }
    }

    // epilogue: store h + fused attention projections
    float4 asv = *(const float4*)(a_src + tc * 4);   // [H,C] flat == channel idx
    float4 adv = *(const float4*)(a_dst + tc * 4);
    int head = tc >> 3;                              // (tc*4)/32
    #pragma unroll
    for (int j = 0; j < 8; j++) {
        int rr = row0 + tr * 8 + j;
        float ps = acc[j][0] * asv.x + acc[j][1] * asv.y + acc[j][2] * asv.z + acc[j][3] * asv.w;
        float pd = acc[j][0] * adv.x + acc[j][1] * adv.y + acc[j][2] * adv.z + acc[j][3] * adv.w;
        ps += __shfl_xor(ps, 1); pd += __shfl_xor(pd, 1);
        ps += __shfl_xor(ps, 2); pd += __shfl_xor(pd, 2);
        ps += __shfl_xor(ps, 4); pd += __shfl_xor(pd, 4);
        if (rr < NN) {
            *(float4*)(&h[(size_t)rr * 128 + tc * 4]) =
                make_float4(acc[j][0], acc[j][1], acc[j][2], acc[j][3]);
            if ((tc & 7) == 0) {
                als[rr * 4 + head] = ps;
                ald[rr * 4 + head] = pd;
            }
        }
    }
}

// ---------------- per-node softmax aggregation (one wave per node) ----------------
// no max pass: p = exp(lrelu(e)) directly (logits are O(1); identical up to rounding)
__launch_bounds__(256)
__global__ void agg_kernel(const float* __restrict__ h, const float* __restrict__ als_,
                           const float* __restrict__ ald_, const int* __restrict__ row_start,
                           const int* __restrict__ src_sorted, const float* __restrict__ bias,
                           float* __restrict__ out) {
    __shared__ float lds_p[4][4][64];   // [wave][head][lane]
    int wid = threadIdx.x >> 6;
    int lane = threadIdx.x & 63;
    int node = blockIdx.x * 4 + wid;
    if (node >= NN) return;
    int hh = lane >> 4;     // head for this lane's 2 channels
    int c = lane * 2;

    float4 adv = *(const float4*)(ald_ + (size_t)node * 4);
    float4 avs = *(const float4*)(als_ + (size_t)node * 4);

    // self-loop
    float p_self = __expf(lrelu(sel4(avs, hh) + sel4(adv, hh)));
    float s_sum = p_self;
    float2 hv = *(const float2*)(h + (size_t)node * 128 + c);
    float acc0 = hv.x * p_self, acc1 = hv.y * p_self;

    int start = row_start[node], end = row_start[node + 1];
    for (int base = start; base < end; base += 64) {
        int j = base + lane;
        int my = 0;
        float4 p4 = make_float4(0.f, 0.f, 0.f, 0.f);
        if (j < end) {
            my = src_sorted[j];
            float4 av = *(const float4*)(als_ + (size_t)my * 4);
            p4.x = __expf(lrelu(av.x + adv.x));
            p4.y = __expf(lrelu(av.y + adv.y));
            p4.z = __expf(lrelu(av.z + adv.z));
            p4.w = __expf(lrelu(av.w + adv.w));
        }
        lds_p[wid][0][lane] = p4.x;
        lds_p[wid][1][lane] = p4.y;
        lds_p[wid][2][lane] = p4.z;
        lds_p[wid][3][lane] = p4.w;
        __builtin_amdgcn_wave_barrier();   // wave-synchronous LDS: pin write->read order

        int cnt = end - base;
        if (cnt > 64) cnt = 64;
        int jj = 0;
        for (; jj + 4 <= cnt; jj += 4) {
            int s0 = __shfl(my, jj + 0);
            int s1 = __shfl(my, jj + 1);
            int s2 = __shfl(my, jj + 2);
            int s3 = __shfl(my, jj + 3);
            float p0 = lds_p[wid][hh][jj + 0];
            float p1 = lds_p[wid][hh][jj + 1];
            float p2 = lds_p[wid][hh][jj + 2];
            float p3 = lds_p[wid][hh][jj + 3];
            float2 h0 = *(const float2*)(h + (size_t)s0 * 128 + c);
            float2 h1 = *(const float2*)(h + (size_t)s1 * 128 + c);
            float2 h2 = *(const float2*)(h + (size_t)s2 * 128 + c);
            float2 h3 = *(const float2*)(h + (size_t)s3 * 128 + c);
            s_sum += p0 + p1 + p2 + p3;
            acc0 += h0.x * p0; acc1 += h0.y * p0;
            acc0 += h1.x * p1; acc1 += h1.y * p1;
            acc0 += h2.x * p2; acc1 += h2.y * p2;
            acc0 += h3.x * p3; acc1 += h3.y * p3;
        }
        for (; jj < cnt; jj++) {
            int s = __shfl(my, jj);
            float p = lds_p[wid][hh][jj];
            float2 hv2 = *(const float2*)(h + (size_t)s * 128 + c);
            s_sum += p;
            acc0 += hv2.x * p;
            acc1 += hv2.y * p;
        }
        __builtin_amdgcn_wave_barrier();   // keep next chunk's writes after reads
    }
    float inv = 1.0f / (s_sum + 1e-16f);
    float2 bv = *(const float2*)(bias + c);
    float o0 = gelu_f(acc0 * inv + bv.x);
    float o1 = gelu_f(acc1 * inv + bv.y);
    *(float2*)(out + (size_t)node * 128 + c) = make_float2(o0, o1);
}

extern "C" void kernel_launch(void* const* d_in, const int* in_sizes, int n_in,
                              void* d_out, int out_size, void* d_ws, size_t ws_size,
                              hipStream_t stream) {
    const int*   label = (const int*)d_in[0];
    const int*   eidx  = (const int*)d_in[1];          // [2, NE]
    const float* rq    = (const float*)d_in[3];
    const float* emb   = (const float*)d_in[4];
    const float* reqW  = (const float*)d_in[5];
    const float* reqb  = (const float*)d_in[6];
    const float* W[3]    = {(const float*)d_in[7],  (const float*)d_in[11], (const float*)d_in[15]};
    const float* asrc[3] = {(const float*)d_in[8],  (const float*)d_in[12], (const float*)d_in[16]};
    const float* adst[3] = {(const float*)d_in[9],  (const float*)d_in[13], (const float*)d_in[17]};
    const float* bias[3] = {(const float*)d_in[10], (const float*)d_in[14], (const float*)d_in[18]};

    const int* e_src = eidx;
    const int* e_dst = eidx + NE;

    char* ws = (char*)d_ws;
    size_t off = 0;
    auto A = [&](size_t n) { size_t o = off; off += (n + 255) & ~(size_t)255; return o; };
    size_t o_deg   = A((size_t)NN * 4);        // zeroed
    size_t o_cur   = A((size_t)NN * 4);        // zeroed
    size_t o_stats = A(8);                     // zeroed
    size_t zero_bytes = off;
    size_t o_row   = A((size_t)(NN + 1) * 4);
    size_t o_bsum  = A(256 * 4);
    size_t o_srcS  = A((size_t)NE * 4);
    size_t o_x     = A((size_t)NN * 128 * 4);
    size_t o_h     = A((size_t)NN * 128 * 4);
    size_t o_als   = A((size_t)NN * 4 * 4);
    size_t o_ald   = A((size_t)NN * 4 * 4);
    (void)ws_size; (void)n_in; (void)in_sizes; (void)out_size;

    int*   deg    = (int*)(ws + o_deg);
    int*   cursor = (int*)(ws + o_cur);
    float* stats  = (float*)(ws + o_stats);
    int*   rowst  = (int*)(ws + o_row);
    int*   bsum   = (int*)(ws + o_bsum);
    int*   srcS   = (int*)(ws + o_srcS);
    float* x      = (float*)(ws + o_x);
    float* h      = (float*)(ws + o_h);
    float* als    = (float*)(ws + o_als);
    float* ald    = (float*)(ws + o_ald);

    hipMemsetAsync(ws, 0, zero_bytes, stream);

    // frontend
    stats_kernel<<<256, 256, 0, stream>>>(rq, stats);
    build_x_kernel<<<4096, 256, 0, stream>>>(label, rq, emb, reqW, reqb, stats, x);

    // CSR build (self-loops handled analytically in agg)
    const int nb_scan = (NN + 255) / 256;  // 196
    hist_kernel<<<(NE + 255) / 256, 256, 0, stream>>>(e_dst, deg);
    scan1_kernel<<<nb_scan, 256, 0, stream>>>(deg, rowst, bsum);
    scan2_kernel<<<1, 256, 0, stream>>>(bsum, nb_scan);
    scan3_kernel<<<nb_scan, 256, 0, stream>>>(rowst, bsum);
    scatter_kernel<<<(NE + 255) / 256, 256, 0, stream>>>(e_src, e_dst, rowst, cursor, srcS);

    // 3 GAT layers
    const int gemm_blocks = (NN + 63) / 64;        // 782
    const int agg_blocks = (NN + 3) / 4;           // 12500
    float* xin = x;
    for (int l = 0; l < 3; l++) {
        gemm_al_kernel<<<gemm_blocks, 256, 0, stream>>>(xin, W[l], asrc[l], adst[l], h, als, ald);
        float* dst_buf = (l == 2) ? (float*)d_out : x;
        agg_kernel<<<agg_blocks, 256, 0, stream>>>(h, als, ald, rowst, srcS, bias[l], dst_buf);
        xin = x;
    }
}

// Round 3
// 481.872 us; speedup vs baseline: 1.3095x; 1.0388x over previous
//
#include <hip/hip_runtime.h>
#include <math.h>

#define NN 50000
#define NE 800000
#define HC 128
#define NHEAD 4
#define EMB 64
#define BK 32

__device__ __forceinline__ float lrelu(float x) { return x > 0.0f ? x : 0.2f * x; }
__device__ __forceinline__ float gelu_f(float x) {
    return 0.5f * x * (1.0f + erff(x * 0.70710678118654752440f));
}
__device__ __forceinline__ float sel4(float4 v, int h) {
    float r = v.x;
    r = (h == 1) ? v.y : r;
    r = (h == 2) ? v.z : r;
    r = (h == 3) ? v.w : r;
    return r;
}

// ---------------- frontend ----------------
__global__ void stats_kernel(const float* __restrict__ rq, float* __restrict__ stats) {
    int i = blockIdx.x * blockDim.x + threadIdx.x;
    float s = 0.f, s2 = 0.f;
    for (; i < NN; i += gridDim.x * blockDim.x) {
        float v = rq[i];
        s += v; s2 += v * v;
    }
    #pragma unroll
    for (int off = 32; off > 0; off >>= 1) {
        s  += __shfl_down(s, off);
        s2 += __shfl_down(s2, off);
    }
    __shared__ float ls[8], ls2[8];
    int lane = threadIdx.x & 63, wid = threadIdx.x >> 6;
    if (lane == 0) { ls[wid] = s; ls2[wid] = s2; }
    __syncthreads();
    if (threadIdx.x == 0) {
        float a = 0.f, b = 0.f;
        int nw = blockDim.x >> 6;
        for (int w = 0; w < nw; w++) { a += ls[w]; b += ls2[w]; }
        atomicAdd(&stats[0], a);
        atomicAdd(&stats[1], b);
    }
}

// one float4 per thread over [NN, 32] float4 slots
__global__ void build_x_kernel(const int* __restrict__ label, const float* __restrict__ rq,
                               const float* __restrict__ emb, const float* __restrict__ reqW,
                               const float* __restrict__ reqb, const float* __restrict__ stats,
                               float* __restrict__ x) {
    int idx = blockIdx.x * blockDim.x + threadIdx.x;
    const int total = NN * 32;
    if (idx >= total) return;
    float sum = stats[0], sumsq = stats[1];
    float mean = sum / (float)NN;
    float var = (sumsq - sum * sum / (float)NN) / (float)(NN - 1);
    float inv = 1.0f / (sqrtf(var) + 1e-6f);
    int n = idx >> 5, q = idx & 31;
    float4 v;
    if (q < 16) {
        v = ((const float4*)(emb + (size_t)label[n] * EMB))[q];
    } else {
        float r = (rq[n] - mean) * inv;
        float4 w = ((const float4*)reqW)[q - 16];
        float4 b = ((const float4*)reqb)[q - 16];
        v = make_float4(r * w.x + b.x, r * w.y + b.y, r * w.z + b.z, r * w.w + b.w);
    }
    ((float4*)x)[idx] = v;
}

// ---------------- CSR build ----------------
__global__ void hist_kernel(const int* __restrict__ dst, int* __restrict__ deg) {
    int i = blockIdx.x * blockDim.x + threadIdx.x;
    if (i < NE) atomicAdd(&deg[dst[i]], 1);
}

__global__ void scan1_kernel(const int* __restrict__ deg, int* __restrict__ row_excl,
                             int* __restrict__ bsum) {
    __shared__ int tmp[256];
    int t = threadIdx.x;
    int i = blockIdx.x * 256 + t;
    int v = (i < NN) ? deg[i] : 0;
    tmp[t] = v;
    __syncthreads();
    #pragma unroll
    for (int off = 1; off < 256; off <<= 1) {
        int add = (t >= off) ? tmp[t - off] : 0;
        __syncthreads();
        tmp[t] += add;
        __syncthreads();
    }
    if (i < NN) row_excl[i] = tmp[t] - v;
    if (t == 255) bsum[blockIdx.x] = tmp[255];
}

__global__ void scan2_kernel(int* __restrict__ bsum, int nb) {
    __shared__ int tmp[256];
    int t = threadIdx.x;
    int v = (t < nb) ? bsum[t] : 0;
    tmp[t] = v;
    __syncthreads();
    #pragma unroll
    for (int off = 1; off < 256; off <<= 1) {
        int add = (t >= off) ? tmp[t - off] : 0;
        __syncthreads();
        tmp[t] += add;
        __syncthreads();
    }
    if (t < nb) bsum[t] = tmp[t] - v;  // exclusive block offsets
}

__global__ void scan3_kernel(int* __restrict__ row_excl, const int* __restrict__ bsum) {
    int i = blockIdx.x * blockDim.x + threadIdx.x;
    if (i < NN) row_excl[i] += bsum[i >> 8];
    if (i == 0) row_excl[NN] = NE;
}

// fills segments back-to-front via atomicSub on deg (deg ends at 0; not reused)
__global__ void scatter_kernel(const int* __restrict__ src, const int* __restrict__ dst,
                               const int* __restrict__ row_start, int* __restrict__ deg,
                               int* __restrict__ src_sorted) {
    int i = blockIdx.x * blockDim.x + threadIdx.x;
    if (i < NE) {
        int d = dst[i];
        int pos = row_start[d] + atomicSub(&deg[d], 1) - 1;
        src_sorted[pos] = src[i];
    }
}

// ---- fused GEMM + attention projections: h = x@W ; als/ald = per-head dot ----
// block: 256 thr; 64 rows x 128 cols out. K-chunked LDS; b128 LDS reads.
__launch_bounds__(256)
__global__ void gemm_al_kernel(const float* __restrict__ x, const float* __restrict__ W,
                               const float* __restrict__ a_src, const float* __restrict__ a_dst,
                               float* __restrict__ h, float* __restrict__ als,
                               float* __restrict__ ald) {
    __shared__ float sW[BK][128];    // 16 KB
    __shared__ float sX[BK][68];     // [k][row], pad 68 keeps 16B align + conflict-free
    int t = threadIdx.x;
    int row0 = blockIdx.x * 64;
    int tr = t >> 5;   // 0..7 -> rows tr*8..tr*8+7
    int tc = t & 31;   // cols tc*4..tc*4+3

    float acc[8][4] = {};
    for (int kk = 0; kk < 128; kk += BK) {
        if (kk) __syncthreads();
        // stage W chunk [kk..kk+BK) x 128
        #pragma unroll
        for (int i = 0; i < 4; i++)
            ((float4*)&sW[0][0])[t + 256 * i] = ((const float4*)(W + kk * 128))[t + 256 * i];
        // stage x chunk transposed: 64 rows x BK k
        #pragma unroll
        for (int i = 0; i < 2; i++) {
            int ii = t + 256 * i;        // 0..511
            int r = ii >> 3;             // 0..63
            int k4 = ii & 7;             // float4 index within BK
            int rr = row0 + r;
            float4 v = make_float4(0.f, 0.f, 0.f, 0.f);
            if (rr < NN) v = *(const float4*)(x + (size_t)rr * 128 + kk + k4 * 4);
            sX[k4 * 4 + 0][r] = v.x;
            sX[k4 * 4 + 1][r] = v.y;
            sX[k4 * 4 + 2][r] = v.z;
            sX[k4 * 4 + 3][r] = v.w;
        }
        __syncthreads();
        #pragma unroll 4
        for (int k = 0; k < BK; k++) {
            float4 wv = *(const float4*)(&sW[k][tc * 4]);
            float4 x0 = *(const float4*)(&sX[k][tr * 8]);
            float4 x1 = *(const float4*)(&sX[k][tr * 8 + 4]);
            float xr[8] = {x0.x, x0.y, x0.z, x0.w, x1.x, x1.y, x1.z, x1.w};
            #pragma unroll
            for (int j = 0; j < 8; j++) {
                acc[j][0] += xr[j] * wv.x;
                acc[j][1] += xr[j] * wv.y;
                acc[j][2] += xr[j] * wv.z;
                acc[j][3] += xr[j] * wv.w;
            }
        }
    }

    // epilogue: store h + fused attention projections
    float4 asv = *(const float4*)(a_src + tc * 4);   // [H,C] flat == channel idx
    float4 adv = *(const float4*)(a_dst + tc * 4);
    int head = tc >> 3;                              // (tc*4)/32
    #pragma unroll
    for (int j = 0; j < 8; j++) {
        int rr = row0 + tr * 8 + j;
        float ps = acc[j][0] * asv.x + acc[j][1] * asv.y + acc[j][2] * asv.z + acc[j][3] * asv.w;
        float pd = acc[j][0] * adv.x + acc[j][1] * adv.y + acc[j][2] * adv.z + acc[j][3] * adv.w;
        ps += __shfl_xor(ps, 1); pd += __shfl_xor(pd, 1);
        ps += __shfl_xor(ps, 2); pd += __shfl_xor(pd, 2);
        ps += __shfl_xor(ps, 4); pd += __shfl_xor(pd, 4);
        if (rr < NN) {
            *(float4*)(&h[(size_t)rr * 128 + tc * 4]) =
                make_float4(acc[j][0], acc[j][1], acc[j][2], acc[j][3]);
            if ((tc & 7) == 0) {
                als[rr * 4 + head] = ps;
                ald[rr * 4 + head] = pd;
            }
        }
    }
}

// ---------------- per-node softmax aggregation ----------------
// one wave per node; lane = (edge-slot sub 0..3, channel-group cg 0..15, 8 ch each)
// p = exp(lrelu(e)) directly (no max pass; logits O(1), identical up to rounding)
__launch_bounds__(256)
__global__ void agg_kernel(const float* __restrict__ h, const float* __restrict__ als_,
                           const float* __restrict__ ald_, const int* __restrict__ row_start,
                           const int* __restrict__ src_sorted, const float* __restrict__ bias,
                           float* __restrict__ out) {
    __shared__ float lds_p[4][4][65];   // [wave][head][edge], pad 65 breaks head-bank overlap
    __shared__ int   lds_s[4][64];
    int wid = threadIdx.x >> 6;
    int lane = threadIdx.x & 63;
    int node = blockIdx.x * 4 + wid;
    if (node >= NN) return;
    int sub  = lane >> 4;    // edge slot
    int cg   = lane & 15;    // channel group
    int c0   = cg * 8;
    int head = cg >> 2;

    float4 adv = *(const float4*)(ald_ + (size_t)node * 4);
    float4 avs = *(const float4*)(als_ + (size_t)node * 4);

    // self-loop (only sub==0 contributes; reduced at the end)
    float p_self = __expf(lrelu(sel4(avs, head) + sel4(adv, head)));
    float pinit = (sub == 0) ? p_self : 0.f;
    float s_sum = pinit;
    const float* hn = h + (size_t)node * 128 + c0;
    float4 hs0 = *(const float4*)hn;
    float4 hs1 = *(const float4*)(hn + 4);
    float acc[8] = {hs0.x * pinit, hs0.y * pinit, hs0.z * pinit, hs0.w * pinit,
                    hs1.x * pinit, hs1.y * pinit, hs1.z * pinit, hs1.w * pinit};

    int start = row_start[node], end = row_start[node + 1];
    for (int base = start; base < end; base += 64) {
        int j = base + lane;
        int my = 0;
        float4 p4 = make_float4(0.f, 0.f, 0.f, 0.f);
        if (j < end) {
            my = src_sorted[j];
            float4 av = *(const float4*)(als_ + (size_t)my * 4);
            p4.x = __expf(lrelu(av.x + adv.x));
            p4.y = __expf(lrelu(av.y + adv.y));
            p4.z = __expf(lrelu(av.z + adv.z));
            p4.w = __expf(lrelu(av.w + adv.w));
        }
        lds_s[wid][lane] = my;
        lds_p[wid][0][lane] = p4.x;
        lds_p[wid][1][lane] = p4.y;
        lds_p[wid][2][lane] = p4.z;
        lds_p[wid][3][lane] = p4.w;
        __builtin_amdgcn_wave_barrier();

        int cnt = end - base;
        if (cnt > 64) cnt = 64;
        for (int jj = 0; jj < cnt; jj += 8) {
            int e0 = jj + sub, e1 = jj + 4 + sub;
            bool v0 = e0 < cnt, v1 = e1 < cnt;
            int s0 = lds_s[wid][v0 ? e0 : 0];
            int s1 = lds_s[wid][v1 ? e1 : 0];
            float p0 = v0 ? lds_p[wid][head][e0] : 0.f;
            float p1 = v1 ? lds_p[wid][head][e1] : 0.f;
            const float* hp0 = h + (size_t)s0 * 128 + c0;
            const float* hp1 = h + (size_t)s1 * 128 + c0;
            float4 a0 = *(const float4*)hp0;
            float4 b0 = *(const float4*)(hp0 + 4);
            float4 a1 = *(const float4*)hp1;
            float4 b1 = *(const float4*)(hp1 + 4);
            s_sum += p0 + p1;
            acc[0] += a0.x * p0; acc[1] += a0.y * p0; acc[2] += a0.z * p0; acc[3] += a0.w * p0;
            acc[4] += b0.x * p0; acc[5] += b0.y * p0; acc[6] += b0.z * p0; acc[7] += b0.w * p0;
            acc[0] += a1.x * p1; acc[1] += a1.y * p1; acc[2] += a1.z * p1; acc[3] += a1.w * p1;
            acc[4] += b1.x * p1; acc[5] += b1.y * p1; acc[6] += b1.z * p1; acc[7] += b1.w * p1;
        }
        __builtin_amdgcn_wave_barrier();
    }

    // reduce partial sums across the 4 edge slots
    #pragma unroll
    for (int i = 0; i < 8; i++) {
        acc[i] += __shfl_xor(acc[i], 16);
        acc[i] += __shfl_xor(acc[i], 32);
    }
    s_sum += __shfl_xor(s_sum, 16);
    s_sum += __shfl_xor(s_sum, 32);

    if (sub == 0) {
        float inv = 1.0f / (s_sum + 1e-16f);
        float4 bv0 = *(const float4*)(bias + c0);
        float4 bv1 = *(const float4*)(bias + c0 + 4);
        float4 o0 = make_float4(gelu_f(acc[0] * inv + bv0.x), gelu_f(acc[1] * inv + bv0.y),
                                gelu_f(acc[2] * inv + bv0.z), gelu_f(acc[3] * inv + bv0.w));
        float4 o1 = make_float4(gelu_f(acc[4] * inv + bv1.x), gelu_f(acc[5] * inv + bv1.y),
                                gelu_f(acc[6] * inv + bv1.z), gelu_f(acc[7] * inv + bv1.w));
        *(float4*)(out + (size_t)node * 128 + c0) = o0;
        *(float4*)(out + (size_t)node * 128 + c0 + 4) = o1;
    }
}

extern "C" void kernel_launch(void* const* d_in, const int* in_sizes, int n_in,
                              void* d_out, int out_size, void* d_ws, size_t ws_size,
                              hipStream_t stream) {
    const int*   label = (const int*)d_in[0];
    const int*   eidx  = (const int*)d_in[1];          // [2, NE]
    const float* rq    = (const float*)d_in[3];
    const float* emb   = (const float*)d_in[4];
    const float* reqW  = (const float*)d_in[5];
    const float* reqb  = (const float*)d_in[6];
    const float* W[3]    = {(const float*)d_in[7],  (const float*)d_in[11], (const float*)d_in[15]};
    const float* asrc[3] = {(const float*)d_in[8],  (const float*)d_in[12], (const float*)d_in[16]};
    const float* adst[3] = {(const float*)d_in[9],  (const float*)d_in[13], (const float*)d_in[17]};
    const float* bias[3] = {(const float*)d_in[10], (const float*)d_in[14], (const float*)d_in[18]};

    const int* e_src = eidx;
    const int* e_dst = eidx + NE;

    char* ws = (char*)d_ws;
    size_t off = 0;
    auto A = [&](size_t n) { size_t o = off; off += (n + 255) & ~(size_t)255; return o; };
    size_t o_deg   = A((size_t)NN * 4);        // zeroed
    size_t o_stats = A(8);                     // zeroed
    size_t zero_bytes = off;
    size_t o_row   = A((size_t)(NN + 1) * 4);
    size_t o_bsum  = A(256 * 4);
    size_t o_srcS  = A((size_t)NE * 4);
    size_t o_x     = A((size_t)NN * 128 * 4);
    size_t o_h     = A((size_t)NN * 128 * 4);
    size_t o_als   = A((size_t)NN * 4 * 4);
    size_t o_ald   = A((size_t)NN * 4 * 4);
    (void)ws_size; (void)n_in; (void)in_sizes; (void)out_size;

    int*   deg    = (int*)(ws + o_deg);
    float* stats  = (float*)(ws + o_stats);
    int*   rowst  = (int*)(ws + o_row);
    int*   bsum   = (int*)(ws + o_bsum);
    int*   srcS   = (int*)(ws + o_srcS);
    float* x      = (float*)(ws + o_x);
    float* h      = (float*)(ws + o_h);
    float* als    = (float*)(ws + o_als);
    float* ald    = (float*)(ws + o_ald);

    hipMemsetAsync(ws, 0, zero_bytes, stream);

    // frontend
    stats_kernel<<<256, 256, 0, stream>>>(rq, stats);
    build_x_kernel<<<(NN * 32 + 255) / 256, 256, 0, stream>>>(label, rq, emb, reqW, reqb, stats, x);

    // CSR build (self-loops handled analytically in agg)
    const int nb_scan = (NN + 255) / 256;  // 196
    hist_kernel<<<(NE + 255) / 256, 256, 0, stream>>>(e_dst, deg);
    scan1_kernel<<<nb_scan, 256, 0, stream>>>(deg, rowst, bsum);
    scan2_kernel<<<1, 256, 0, stream>>>(bsum, nb_scan);
    scan3_kernel<<<nb_scan, 256, 0, stream>>>(rowst, bsum);
    scatter_kernel<<<(NE + 255) / 256, 256, 0, stream>>>(e_src, e_dst, rowst, deg, srcS);

    // 3 GAT layers
    const int gemm_blocks = (NN + 63) / 64;        // 782
    const int agg_blocks = (NN + 3) / 4;           // 12500
    float* xin = x;
    for (int l = 0; l < 3; l++) {
        gemm_al_kernel<<<gemm_blocks, 256, 0, stream>>>(xin, W[l], asrc[l], adst[l], h, als, ald);
        float* dst_buf = (l == 2) ? (float*)d_out : x;
        agg_kernel<<<agg_blocks, 256, 0, stream>>>(h, als, ald, rowst, srcS, bias[l], dst_buf);
        xin = x;
    }
}